// Round 1
// baseline (1144.047 us; speedup 1.0000x reference)
//
#include <hip/hip_runtime.h>
#include <math.h>

#define E_EDGES 200000
#define N_NODES 10000
#define FDIM    128

typedef __attribute__((ext_vector_type(8))) short  short8;
typedef __attribute__((ext_vector_type(4))) float  float4v;

// ws layout (ushort units): Wt1[128][256] @0, Wtw1[128][128] @32768,
// Wt2[640][128] @49152, Wtw2[640][128] @131072; total 212992 ushorts.
#define WT1_OFF   0
#define WTW1_OFF  32768
#define WT2_OFF   49152
#define WTW2_OFF  131072
#define W_TOTAL   212992

#define EQ_OUT_SZ   (N_NODES * FDIM * 3)   // 3,840,000
#define INV_OUT_SZ  (N_NODES * FDIM)       // 1,280,000

__device__ __forceinline__ unsigned short f2bf(float x) {
    union { float f; unsigned u; } v; v.f = x;
    unsigned r = v.u + 0x7fffu + ((v.u >> 16) & 1u);
    return (unsigned short)(r >> 16);
}
__device__ __forceinline__ float bf2f(unsigned short h) {
    union { unsigned u; float f; } v; v.u = ((unsigned)h) << 16; return v.f;
}

// ---------------- prep: transpose weights to bf16 [n][k] ----------------
__global__ void prep_weights(const float* __restrict__ phiW1,
                             const float* __restrict__ wW1,
                             const float* __restrict__ phiW2,
                             const float* __restrict__ wW2,
                             unsigned short* __restrict__ ws) {
    int t = blockIdx.x * 256 + threadIdx.x;
    if (t < 32768) {                       // Wt1[n][k] = phiW1[k][n], k<256,n<128
        int n = t >> 8, k = t & 255;
        ws[WT1_OFF + t] = f2bf(phiW1[k * 128 + n]);
    } else if (t < 49152) {                // Wtw1[n][k] = wW1[k][n], 128x128
        int i = t - 32768; int n = i >> 7, k = i & 127;
        ws[WTW1_OFF + i] = f2bf(wW1[k * 128 + n]);
    } else if (t < 131072) {               // Wt2[n][k] = phiW2[k][n], n<640,k<128
        int i = t - 49152; int n = i >> 7, k = i & 127;
        ws[WT2_OFF + i] = f2bf(phiW2[k * 640 + n]);
    } else if (t < W_TOTAL) {              // Wtw2
        int i = t - 131072; int n = i >> 7, k = i & 127;
        ws[WTW2_OFF + i] = f2bf(wW2[k * 640 + n]);
    }
}

// ---------------- init: out[0:eq] = eq, out[eq:+inv] = inv ----------------
__global__ void init_out_k(const float* __restrict__ eq,
                           const float* __restrict__ inv,
                           float* __restrict__ out) {
    int t = blockIdx.x * 256 + threadIdx.x;      // 1,280,000 float4s
    if (t < EQ_OUT_SZ / 4) {
        ((float4v*)out)[t] = ((const float4v*)eq)[t];
    } else {
        int u = t - EQ_OUT_SZ / 4;
        ((float4v*)(out + EQ_OUT_SZ))[u] = ((const float4v*)inv)[u];
    }
}

// ---------------- fused edge kernel: 32 edges / block ----------------
__global__ __launch_bounds__(256)
void edge_kernel(const int*   __restrict__ eidx,
                 const float* __restrict__ node_inv,
                 const float* __restrict__ eqf,
                 const float* __restrict__ edge_inv,
                 const float* __restrict__ dist,
                 const float* __restrict__ dir,
                 const float* __restrict__ phi_b1,
                 const float* __restrict__ phi_b2,
                 const float* __restrict__ w_b1,
                 const float* __restrict__ w_b2,
                 const unsigned short* __restrict__ wsW,
                 float* __restrict__ out) {
    // LDS: pad +8 bf16 -> row stride shifts 4 banks -> 2-way aliasing (free)
    __shared__ unsigned short A1[32][264];   // concat(node_inv[src], edge_inv) bf16
    __shared__ unsigned short A2[32][136];   // positional encoding bf16
    __shared__ unsigned short H1[32][136];   // silu(in@W1+b1) bf16
    __shared__ unsigned short H2[32][136];   // silu(pe@wW1+wb1) bf16
    __shared__ int   s_src[32], s_dst[32];
    __shared__ float s_dir[32][3];

    const int tid = threadIdx.x;
    const int e0  = blockIdx.x * 32;

    if (tid < 32) {
        int e = e0 + tid;
        s_src[tid] = eidx[e];
        s_dst[tid] = eidx[E_EDGES + e];
        s_dir[tid][0] = dir[e * 3 + 0];
        s_dir[tid][1] = dir[e * 3 + 1];
        s_dir[tid][2] = dir[e * 3 + 2];
    }
    __syncthreads();

    // ---- stage A1 (gathered fp32 -> bf16) and A2 (PE) ----
    {
        const int i   = tid >> 3;        // row 0..31
        const int seg = tid & 7;         // 0..7
        const int e   = e0 + i;
        const int k0  = seg * 32;
        const float* base = (k0 < 128)
            ? (node_inv + (size_t)s_src[i] * 128 + k0)
            : (edge_inv + (size_t)e * 128 + (k0 - 128));
        #pragma unroll
        for (int j = 0; j < 4; ++j) {
            float4v v0 = *(const float4v*)(base + j * 8);
            float4v v1 = *(const float4v*)(base + j * 8 + 4);
            short8 sv;
            #pragma unroll
            for (int u = 0; u < 4; ++u) {
                sv[u]     = (short)f2bf(v0[u]);
                sv[u + 4] = (short)f2bf(v1[u]);
            }
            *(short8*)&A1[i][k0 + j * 8] = sv;
        }
        // PE: 16 features per thread
        const float d   = dist[e];
        const float cst = 3.14159265358979323846f / 10.0f;
        #pragma unroll
        for (int j = 0; j < 2; ++j) {
            short8 sv;
            #pragma unroll
            for (int u = 0; u < 8; ++u) {
                int f = seg * 16 + j * 8 + u;
                float val = (f < 64) ? __sinf(d * (float)f * cst)
                                     : __cosf(d * (float)(f - 64) * cst);
                sv[u] = (short)f2bf(val);
            }
            *(short8*)&A2[i][seg * 16 + j * 8] = sv;
        }
    }
    __syncthreads();

    const int wv   = tid >> 6;   // wave 0..3 -> column strip
    const int ln   = tid & 63;
    const int l16  = ln & 15;
    const int quad = ln >> 4;

    const unsigned short* Wt1  = wsW + WT1_OFF;
    const unsigned short* Wtw1 = wsW + WTW1_OFF;
    const unsigned short* Wt2  = wsW + WT2_OFF;
    const unsigned short* Wtw2 = wsW + WTW2_OFF;

    const float4v zero4 = {0.f, 0.f, 0.f, 0.f};

    // ---- phase 1: H1 = silu(A1 @ phiW1 + b1), H2 = silu(A2 @ wW1 + wb1) ----
    float4v acc1[2][2], acc2[2][2];
    #pragma unroll
    for (int rt = 0; rt < 2; ++rt)
        #pragma unroll
        for (int ct = 0; ct < 2; ++ct) { acc1[rt][ct] = zero4; acc2[rt][ct] = zero4; }

    #pragma unroll
    for (int kk = 0; kk < 8; ++kk) {        // K = 256
        const int k = kk * 32 + quad * 8;
        short8 a0 = *(const short8*)&A1[l16][k];
        short8 a1 = *(const short8*)&A1[16 + l16][k];
        #pragma unroll
        for (int ct = 0; ct < 2; ++ct) {
            const int n = wv * 32 + ct * 16 + l16;
            short8 b = *(const short8*)&Wt1[n * 256 + k];
            acc1[0][ct] = __builtin_amdgcn_mfma_f32_16x16x32_bf16(a0, b, acc1[0][ct], 0, 0, 0);
            acc1[1][ct] = __builtin_amdgcn_mfma_f32_16x16x32_bf16(a1, b, acc1[1][ct], 0, 0, 0);
        }
    }
    #pragma unroll
    for (int kk = 0; kk < 4; ++kk) {        // K = 128
        const int k = kk * 32 + quad * 8;
        short8 a0 = *(const short8*)&A2[l16][k];
        short8 a1 = *(const short8*)&A2[16 + l16][k];
        #pragma unroll
        for (int ct = 0; ct < 2; ++ct) {
            const int n = wv * 32 + ct * 16 + l16;
            short8 b = *(const short8*)&Wtw1[n * 128 + k];
            acc2[0][ct] = __builtin_amdgcn_mfma_f32_16x16x32_bf16(a0, b, acc2[0][ct], 0, 0, 0);
            acc2[1][ct] = __builtin_amdgcn_mfma_f32_16x16x32_bf16(a1, b, acc2[1][ct], 0, 0, 0);
        }
    }
    // silu + store H (C/D layout: col = l16, row = quad*4 + reg)
    #pragma unroll
    for (int ct = 0; ct < 2; ++ct) {
        const int n = wv * 32 + ct * 16 + l16;
        const float b1v  = phi_b1[n];
        const float bw1v = w_b1[n];
        #pragma unroll
        for (int rt = 0; rt < 2; ++rt)
            #pragma unroll
            for (int r = 0; r < 4; ++r) {
                const int row = rt * 16 + quad * 4 + r;
                float x = acc1[rt][ct][r] + b1v;
                H1[row][n] = f2bf(x / (1.f + __expf(-x)));
                float y = acc2[rt][ct][r] + bw1v;
                H2[row][n] = f2bf(y / (1.f + __expf(-y)));
            }
    }
    __syncthreads();

    // ---- phase 2: all 5 gate groups per 64-feature chunk, then epilogue ----
    float* eq_out   = out;
    float* inv_out  = out + EQ_OUT_SZ;
    float* edge_out = out + EQ_OUT_SZ + INV_OUT_SZ;

    #pragma unroll
    for (int fc = 0; fc < 2; ++fc) {
        float4v mv[5][2];
        #pragma unroll
        for (int g = 0; g < 5; ++g) {
            const int n = g * 128 + fc * 64 + wv * 16 + l16;   // col in [0,640)
            float4v p1[2] = {zero4, zero4}, p2[2] = {zero4, zero4};
            #pragma unroll
            for (int kk = 0; kk < 4; ++kk) {
                const int k = kk * 32 + quad * 8;
                short8 ha0 = *(const short8*)&H1[l16][k];
                short8 ha1 = *(const short8*)&H1[16 + l16][k];
                short8 hb0 = *(const short8*)&H2[l16][k];
                short8 hb1 = *(const short8*)&H2[16 + l16][k];
                short8 b1f = *(const short8*)&Wt2[n * 128 + k];
                short8 b2f = *(const short8*)&Wtw2[n * 128 + k];
                p1[0] = __builtin_amdgcn_mfma_f32_16x16x32_bf16(ha0, b1f, p1[0], 0, 0, 0);
                p1[1] = __builtin_amdgcn_mfma_f32_16x16x32_bf16(ha1, b1f, p1[1], 0, 0, 0);
                p2[0] = __builtin_amdgcn_mfma_f32_16x16x32_bf16(hb0, b2f, p2[0], 0, 0, 0);
                p2[1] = __builtin_amdgcn_mfma_f32_16x16x32_bf16(hb1, b2f, p2[1], 0, 0, 0);
            }
            const float b2v  = phi_b2[n];
            const float bw2v = w_b2[n];
            #pragma unroll
            for (int rt = 0; rt < 2; ++rt)
                mv[g][rt] = (p1[rt] + b2v) * (p2[rt] + bw2v);
        }
        // epilogue straight from C-layout registers
        const int f = fc * 64 + wv * 16 + l16;
        #pragma unroll
        for (int rt = 0; rt < 2; ++rt) {
            #pragma unroll
            for (int r = 0; r < 4; ++r) {
                const int i = rt * 16 + quad * 4 + r;
                const int e = e0 + i;
                const float gate = mv[0][rt][r];
                const float cpg  = mv[1][rt][r];
                const float sc   = mv[2][rt][r];
                const float dsv  = mv[3][rt][r];
                const float dev  = mv[4][rt][r];
                const int sn = s_src[i], dn = s_dst[i];
                const float ex = s_dir[i][0], ey = s_dir[i][1], ez = s_dir[i][2];
                const float* se = eqf + ((size_t)sn * 128 + f) * 3;
                const float* dq = eqf + ((size_t)dn * 128 + f) * 3;
                const float sx = se[0], sy = se[1], sz = se[2];
                const float dx = dq[0], dy = dq[1], dz = dq[2];
                // cross(edir, dst_eq)
                const float cx = ey * dz - ez * dy;
                const float cy = ez * dx - ex * dz;
                const float cz = ex * dy - ey * dx;
                const float vx = sc * ex + gate * sx + cpg * cx;
                const float vy = sc * ey + gate * sy + cpg * cy;
                const float vz = sc * ez + gate * sz + cpg * cz;
                float* eo = eq_out + ((size_t)dn * 128 + f) * 3;
                atomicAdd(eo + 0, vx);
                atomicAdd(eo + 1, vy);
                atomicAdd(eo + 2, vz);
                atomicAdd(inv_out + (size_t)dn * 128 + f, dsv);
                edge_out[(size_t)e * 128 + f] = bf2f(A1[i][128 + f]) + dev;
            }
        }
    }
}

extern "C" void kernel_launch(void* const* d_in, const int* in_sizes, int n_in,
                              void* d_out, int out_size, void* d_ws, size_t ws_size,
                              hipStream_t stream) {
    const int*   eidx     = (const int*)d_in[0];
    const float* node_inv = (const float*)d_in[1];
    const float* eqf      = (const float*)d_in[2];
    const float* edge_inv = (const float*)d_in[3];
    const float* dist     = (const float*)d_in[4];
    const float* dir      = (const float*)d_in[5];
    const float* phi_W1   = (const float*)d_in[6];
    const float* phi_b1   = (const float*)d_in[7];
    const float* phi_W2   = (const float*)d_in[8];
    const float* phi_b2   = (const float*)d_in[9];
    const float* w_W1     = (const float*)d_in[10];
    const float* w_b1     = (const float*)d_in[11];
    const float* w_W2     = (const float*)d_in[12];
    const float* w_b2     = (const float*)d_in[13];
    float* out = (float*)d_out;
    unsigned short* wsW = (unsigned short*)d_ws;

    prep_weights<<<(W_TOTAL + 255) / 256, 256, 0, stream>>>(phi_W1, w_W1, phi_W2, w_W2, wsW);
    init_out_k<<<(EQ_OUT_SZ + INV_OUT_SZ) / 4 / 256, 256, 0, stream>>>(eqf, node_inv, out);
    edge_kernel<<<E_EDGES / 32, 256, 0, stream>>>(eidx, node_inv, eqf, edge_inv, dist, dir,
                                                  phi_b1, phi_b2, w_b1, w_b2, wsW, out);
}

// Round 2
// 945.494 us; speedup vs baseline: 1.2100x; 1.2100x over previous
//
#include <hip/hip_runtime.h>
#include <math.h>

#define E_EDGES 200000
#define N_NODES 10000
#define FDIM    128

typedef __attribute__((ext_vector_type(8))) short  short8;
typedef __attribute__((ext_vector_type(4))) float  float4v;

// ws layout: bf16 weights (ushort units), then sort scratch (byte offsets).
#define WT1_OFF   0            // Wt1[128][256]
#define WTW1_OFF  32768        // Wtw1[128][128]
#define WT2_OFF   49152        // Wt2[640][128]
#define WTW2_OFF  131072       // Wtw2[640][128]
#define W_TOTAL   212992       // ushorts = 425,984 bytes
#define CNT_BYTE  425984       // counts[10000] int
#define CUR_BYTE  465984       // cursor[10000] int
#define PERM_BYTE 505984       // perm[200000] int  (ends at 1,305,984 B)

#define EQ_OUT_SZ   (N_NODES * FDIM * 3)   // 3,840,000
#define INV_OUT_SZ  (N_NODES * FDIM)       // 1,280,000

__device__ __forceinline__ unsigned short f2bf(float x) {
    union { float f; unsigned u; } v; v.f = x;
    unsigned r = v.u + 0x7fffu + ((v.u >> 16) & 1u);
    return (unsigned short)(r >> 16);
}
__device__ __forceinline__ float bf2f(unsigned short h) {
    union { unsigned u; float f; } v; v.u = ((unsigned)h) << 16; return v.f;
}

// ---------------- prep: transpose weights to bf16 [n][k] ----------------
__global__ void prep_weights(const float* __restrict__ phiW1,
                             const float* __restrict__ wW1,
                             const float* __restrict__ phiW2,
                             const float* __restrict__ wW2,
                             unsigned short* __restrict__ ws) {
    int t = blockIdx.x * 256 + threadIdx.x;
    if (t < 32768) {
        int n = t >> 8, k = t & 255;
        ws[WT1_OFF + t] = f2bf(phiW1[k * 128 + n]);
    } else if (t < 49152) {
        int i = t - 32768; int n = i >> 7, k = i & 127;
        ws[WTW1_OFF + i] = f2bf(wW1[k * 128 + n]);
    } else if (t < 131072) {
        int i = t - 49152; int n = i >> 7, k = i & 127;
        ws[WT2_OFF + i] = f2bf(phiW2[k * 640 + n]);
    } else if (t < W_TOTAL) {
        int i = t - 131072; int n = i >> 7, k = i & 127;
        ws[WTW2_OFF + i] = f2bf(wW2[k * 640 + n]);
    }
}

// ---------------- counting sort by dst ----------------
__global__ void zero_counts(int* __restrict__ counts) {
    int t = blockIdx.x * 256 + threadIdx.x;
    if (t < N_NODES) counts[t] = 0;
}
__global__ void hist_kernel(const int* __restrict__ eidx, int* __restrict__ counts) {
    int e = blockIdx.x * 256 + threadIdx.x;
    if (e < E_EDGES) atomicAdd(&counts[eidx[E_EDGES + e]], 1);
}
__global__ __launch_bounds__(1024)
void scan_kernel(const int* __restrict__ counts, int* __restrict__ cursor) {
    __shared__ int sums[1024];
    const int t = threadIdx.x;
    const int base = t * 10;                 // 1024*10 >= 10000
    int local[10];
    int s = 0;
    #pragma unroll
    for (int j = 0; j < 10; ++j) {
        int b = base + j;
        int v = (b < N_NODES) ? counts[b] : 0;
        local[j] = s; s += v;
    }
    sums[t] = s;
    __syncthreads();
    for (int off = 1; off < 1024; off <<= 1) {
        int v = (t >= off) ? sums[t - off] : 0;
        __syncthreads();
        sums[t] += v;
        __syncthreads();
    }
    int pre = (t > 0) ? sums[t - 1] : 0;
    #pragma unroll
    for (int j = 0; j < 10; ++j) {
        int b = base + j;
        if (b < N_NODES) cursor[b] = pre + local[j];
    }
}
__global__ void scatter_kernel(const int* __restrict__ eidx,
                               int* __restrict__ cursor, int* __restrict__ perm) {
    int e = blockIdx.x * 256 + threadIdx.x;
    if (e < E_EDGES) {
        int d = eidx[E_EDGES + e];
        int pos = atomicAdd(&cursor[d], 1);
        perm[pos] = e;
    }
}

// ---------------- init: out[0:eq] = eq, out[eq:+inv] = inv ----------------
__global__ void init_out_k(const float* __restrict__ eq,
                           const float* __restrict__ inv,
                           float* __restrict__ out) {
    int t = blockIdx.x * 256 + threadIdx.x;
    if (t < EQ_OUT_SZ / 4) {
        ((float4v*)out)[t] = ((const float4v*)eq)[t];
    } else {
        int u = t - EQ_OUT_SZ / 4;
        ((float4v*)(out + EQ_OUT_SZ))[u] = ((const float4v*)inv)[u];
    }
}

// ---------------- fused edge kernel: 32 sorted edges / block ----------------
__global__ __launch_bounds__(256)
void edge_kernel(const int*   __restrict__ eidx,
                 const float* __restrict__ node_inv,
                 const float* __restrict__ eqf,
                 const float* __restrict__ edge_inv,
                 const float* __restrict__ dist,
                 const float* __restrict__ dir,
                 const float* __restrict__ phi_b1,
                 const float* __restrict__ phi_b2,
                 const float* __restrict__ w_b1,
                 const float* __restrict__ w_b2,
                 const unsigned short* __restrict__ wsW,
                 const int* __restrict__ perm,
                 float* __restrict__ out) {
    // union region: phase-A/1 holds A1a|A2 (17,408 B); epilogue holds dv[32][32][4] f32 (16,384 B)
    __shared__ __align__(16) unsigned char smem_u[17408];
    __shared__ unsigned short A1b[32][136];   // edge_inv bf16 (kept through epilogue)
    __shared__ unsigned short H1[32][136];
    __shared__ unsigned short H2[32][136];
    __shared__ int   s_e[32], s_src[32], s_dst[32];
    __shared__ float s_dir[32][3];

    unsigned short (*A1a)[136] = (unsigned short (*)[136])smem_u;
    unsigned short (*A2)[136]  = (unsigned short (*)[136])(smem_u + 8704);
    float (*DVS)[32][4]        = (float (*)[32][4])smem_u;

    const int tid = threadIdx.x;
    const int p0  = blockIdx.x * 32;

    if (tid < 32) {
        int e = perm[p0 + tid];
        s_e[tid]   = e;
        s_src[tid] = eidx[e];
        s_dst[tid] = eidx[E_EDGES + e];
        s_dir[tid][0] = dir[e * 3 + 0];
        s_dir[tid][1] = dir[e * 3 + 1];
        s_dir[tid][2] = dir[e * 3 + 2];
    }
    __syncthreads();

    // ---- stage A1a (node_inv[src]), A1b (edge_inv[e]), A2 (PE) as bf16 ----
    {
        const int i   = tid >> 3;        // row 0..31
        const int seg = tid & 7;         // 0..7
        const int e   = s_e[i];
        const int k0  = seg * 32;
        const float* base = (k0 < 128)
            ? (node_inv + (size_t)s_src[i] * 128 + k0)
            : (edge_inv + (size_t)e * 128 + (k0 - 128));
        unsigned short* dst_ls = (k0 < 128) ? &A1a[i][k0] : &A1b[i][k0 - 128];
        #pragma unroll
        for (int j = 0; j < 4; ++j) {
            float4v v0 = *(const float4v*)(base + j * 8);
            float4v v1 = *(const float4v*)(base + j * 8 + 4);
            short8 sv;
            #pragma unroll
            for (int u = 0; u < 4; ++u) {
                sv[u]     = (short)f2bf(v0[u]);
                sv[u + 4] = (short)f2bf(v1[u]);
            }
            *(short8*)(dst_ls + j * 8) = sv;
        }
        const float d   = dist[e];
        const float cst = 3.14159265358979323846f / 10.0f;
        #pragma unroll
        for (int j = 0; j < 2; ++j) {
            short8 sv;
            #pragma unroll
            for (int u = 0; u < 8; ++u) {
                int f = seg * 16 + j * 8 + u;
                float val = (f < 64) ? __sinf(d * (float)f * cst)
                                     : __cosf(d * (float)(f - 64) * cst);
                sv[u] = (short)f2bf(val);
            }
            *(short8*)&A2[i][seg * 16 + j * 8] = sv;
        }
    }
    __syncthreads();

    const int wv   = tid >> 6;
    const int ln   = tid & 63;
    const int l16  = ln & 15;
    const int quad = ln >> 4;

    const unsigned short* Wt1  = wsW + WT1_OFF;
    const unsigned short* Wtw1 = wsW + WTW1_OFF;
    const unsigned short* Wt2  = wsW + WT2_OFF;
    const unsigned short* Wtw2 = wsW + WTW2_OFF;

    const float4v zero4 = {0.f, 0.f, 0.f, 0.f};

    // ---- phase 1: H1 = silu(A1 @ phiW1 + b1), H2 = silu(A2 @ wW1 + wb1) ----
    float4v acc1[2][2], acc2[2][2];
    #pragma unroll
    for (int rt = 0; rt < 2; ++rt)
        #pragma unroll
        for (int ct = 0; ct < 2; ++ct) { acc1[rt][ct] = zero4; acc2[rt][ct] = zero4; }

    #pragma unroll
    for (int kk = 0; kk < 4; ++kk) {        // K 0..127 (node part)
        const int k = kk * 32 + quad * 8;
        short8 a0 = *(const short8*)&A1a[l16][k];
        short8 a1 = *(const short8*)&A1a[16 + l16][k];
        #pragma unroll
        for (int ct = 0; ct < 2; ++ct) {
            const int n = wv * 32 + ct * 16 + l16;
            short8 b = *(const short8*)&Wt1[n * 256 + k];
            acc1[0][ct] = __builtin_amdgcn_mfma_f32_16x16x32_bf16(a0, b, acc1[0][ct], 0, 0, 0);
            acc1[1][ct] = __builtin_amdgcn_mfma_f32_16x16x32_bf16(a1, b, acc1[1][ct], 0, 0, 0);
        }
    }
    #pragma unroll
    for (int kk = 0; kk < 4; ++kk) {        // K 128..255 (edge part)
        const int k = kk * 32 + quad * 8;
        short8 a0 = *(const short8*)&A1b[l16][k];
        short8 a1 = *(const short8*)&A1b[16 + l16][k];
        #pragma unroll
        for (int ct = 0; ct < 2; ++ct) {
            const int n = wv * 32 + ct * 16 + l16;
            short8 b = *(const short8*)&Wt1[n * 256 + 128 + k];
            acc1[0][ct] = __builtin_amdgcn_mfma_f32_16x16x32_bf16(a0, b, acc1[0][ct], 0, 0, 0);
            acc1[1][ct] = __builtin_amdgcn_mfma_f32_16x16x32_bf16(a1, b, acc1[1][ct], 0, 0, 0);
        }
    }
    #pragma unroll
    for (int kk = 0; kk < 4; ++kk) {        // PE, K = 128
        const int k = kk * 32 + quad * 8;
        short8 a0 = *(const short8*)&A2[l16][k];
        short8 a1 = *(const short8*)&A2[16 + l16][k];
        #pragma unroll
        for (int ct = 0; ct < 2; ++ct) {
            const int n = wv * 32 + ct * 16 + l16;
            short8 b = *(const short8*)&Wtw1[n * 128 + k];
            acc2[0][ct] = __builtin_amdgcn_mfma_f32_16x16x32_bf16(a0, b, acc2[0][ct], 0, 0, 0);
            acc2[1][ct] = __builtin_amdgcn_mfma_f32_16x16x32_bf16(a1, b, acc2[1][ct], 0, 0, 0);
        }
    }
    // silu + store H (C/D: col = l16, row = quad*4 + reg)
    #pragma unroll
    for (int ct = 0; ct < 2; ++ct) {
        const int n = wv * 32 + ct * 16 + l16;
        const float b1v  = phi_b1[n];
        const float bw1v = w_b1[n];
        #pragma unroll
        for (int rt = 0; rt < 2; ++rt)
            #pragma unroll
            for (int r = 0; r < 4; ++r) {
                const int row = rt * 16 + quad * 4 + r;
                float x = acc1[rt][ct][r] + b1v;
                H1[row][n] = f2bf(x / (1.f + __expf(-x)));
                float y = acc2[rt][ct][r] + bw1v;
                H2[row][n] = f2bf(y / (1.f + __expf(-y)));
            }
    }
    __syncthreads();      // H ready; A1a/A2 region free from here on

    // ---- phase 2: 4 chunks of 32 features; per chunk: 5 gate GEMMs + epilogue ----
    float* eq_out   = out;
    float* inv_out  = out + EQ_OUT_SZ;
    float* edge_out = out + EQ_OUT_SZ + INV_OUT_SZ;

    const int wvl = wv & 1;      // column half within 32-feature chunk
    const int wvh = wv >> 1;     // row half (edges 0-15 / 16-31)

    // hoist A-fragments (fc/g-invariant)
    short8 ha[4], hb[4];
    #pragma unroll
    for (int kk = 0; kk < 4; ++kk) {
        const int k = kk * 32 + quad * 8;
        ha[kk] = *(const short8*)&H1[wvh * 16 + l16][k];
        hb[kk] = *(const short8*)&H2[wvh * 16 + l16][k];
    }

    const int red_half = tid >> 7;          // reduction pass mapping
    const int red_f    = (tid >> 2) & 31;
    const int red_c    = tid & 3;

    #pragma unroll
    for (int fc = 0; fc < 4; ++fc) {
        float4v mv[5];
        #pragma unroll
        for (int g = 0; g < 5; ++g) {
            const int n = g * 128 + fc * 32 + wvl * 16 + l16;
            float4v p1 = zero4, p2 = zero4;
            #pragma unroll
            for (int kk = 0; kk < 4; ++kk) {
                const int k = kk * 32 + quad * 8;
                short8 b1f = *(const short8*)&Wt2[n * 128 + k];
                short8 b2f = *(const short8*)&Wtw2[n * 128 + k];
                p1 = __builtin_amdgcn_mfma_f32_16x16x32_bf16(ha[kk], b1f, p1, 0, 0, 0);
                p2 = __builtin_amdgcn_mfma_f32_16x16x32_bf16(hb[kk], b2f, p2, 0, 0, 0);
            }
            const float b2v  = phi_b2[n];
            const float bw2v = w_b2[n];
            mv[g] = (p1 + b2v) * (p2 + bw2v);
        }
        // stage per-edge dv/ds to LDS + write edge_out
        const int fl = wvl * 16 + l16;      // 0..31
        const int fg = fc * 32 + fl;
        #pragma unroll
        for (int r = 0; r < 4; ++r) {
            const int row = wvh * 16 + quad * 4 + r;
            const float gate = mv[0][r];
            const float cpg  = mv[1][r];
            const float sc   = mv[2][r];
            const float dsv  = mv[3][r];
            const float dev  = mv[4][r];
            const int sn = s_src[row], dn = s_dst[row], e = s_e[row];
            const float ex = s_dir[row][0], ey = s_dir[row][1], ez = s_dir[row][2];
            const float* se = eqf + ((size_t)sn * 128 + fg) * 3;
            const float* dq = eqf + ((size_t)dn * 128 + fg) * 3;
            const float sx = se[0], sy = se[1], sz = se[2];
            const float dx = dq[0], dy = dq[1], dz = dq[2];
            const float cx = ey * dz - ez * dy;
            const float cy = ez * dx - ex * dz;
            const float cz = ex * dy - ey * dx;
            float4v v;
            v[0] = sc * ex + gate * sx + cpg * cx;
            v[1] = sc * ey + gate * sy + cpg * cy;
            v[2] = sc * ez + gate * sz + cpg * cz;
            v[3] = dsv;
            *(float4v*)&DVS[row][fl] = v;
            edge_out[(size_t)e * 128 + fg] = bf2f(A1b[row][fg]) + dev;
        }
        __syncthreads();
        // segmented reduction over sorted-dst rows: ~1 atomic per run
        {
            const int fgr = fc * 32 + red_f;
            float acc = 0.f;
            int prev = s_dst[red_half * 16];
            #pragma unroll
            for (int r = 0; r < 16; ++r) {
                const int row = red_half * 16 + r;
                const int d = s_dst[row];
                const float v = DVS[row][red_f][red_c];
                if (d != prev) {
                    if (red_c < 3) atomicAdd(eq_out + ((size_t)prev * 128 + fgr) * 3 + red_c, acc);
                    else           atomicAdd(inv_out + (size_t)prev * 128 + fgr, acc);
                    acc = 0.f; prev = d;
                }
                acc += v;
            }
            if (red_c < 3) atomicAdd(eq_out + ((size_t)prev * 128 + fgr) * 3 + red_c, acc);
            else           atomicAdd(inv_out + (size_t)prev * 128 + fgr, acc);
        }
        __syncthreads();
    }
}

extern "C" void kernel_launch(void* const* d_in, const int* in_sizes, int n_in,
                              void* d_out, int out_size, void* d_ws, size_t ws_size,
                              hipStream_t stream) {
    const int*   eidx     = (const int*)d_in[0];
    const float* node_inv = (const float*)d_in[1];
    const float* eqf      = (const float*)d_in[2];
    const float* edge_inv = (const float*)d_in[3];
    const float* dist     = (const float*)d_in[4];
    const float* dir      = (const float*)d_in[5];
    const float* phi_W1   = (const float*)d_in[6];
    const float* phi_b1   = (const float*)d_in[7];
    const float* phi_W2   = (const float*)d_in[8];
    const float* phi_b2   = (const float*)d_in[9];
    const float* w_W1     = (const float*)d_in[10];
    const float* w_b1     = (const float*)d_in[11];
    const float* w_W2     = (const float*)d_in[12];
    const float* w_b2     = (const float*)d_in[13];
    float* out = (float*)d_out;
    unsigned short* wsW = (unsigned short*)d_ws;
    int* counts = (int*)((char*)d_ws + CNT_BYTE);
    int* cursor = (int*)((char*)d_ws + CUR_BYTE);
    int* perm   = (int*)((char*)d_ws + PERM_BYTE);

    zero_counts<<<(N_NODES + 255) / 256, 256, 0, stream>>>(counts);
    hist_kernel<<<(E_EDGES + 255) / 256, 256, 0, stream>>>(eidx, counts);
    scan_kernel<<<1, 1024, 0, stream>>>(counts, cursor);
    scatter_kernel<<<(E_EDGES + 255) / 256, 256, 0, stream>>>(eidx, cursor, perm);
    prep_weights<<<(W_TOTAL + 255) / 256, 256, 0, stream>>>(phi_W1, w_W1, phi_W2, w_W2, wsW);
    init_out_k<<<(EQ_OUT_SZ + INV_OUT_SZ) / 4 / 256, 256, 0, stream>>>(eqf, node_inv, out);
    edge_kernel<<<E_EDGES / 32, 256, 0, stream>>>(eidx, node_inv, eqf, edge_inv, dist, dir,
                                                  phi_b1, phi_b2, w_b1, w_b2, wsW, perm, out);
}